// Round 6
// baseline (452.324 us; speedup 1.0000x reference)
//
#include <hip/hip_runtime.h>
#include <hip/hip_bf16.h>

#define NB 8
#define PP 256
#define CC 128
#define APAD 136   // padded k-stride for Bs (bf16 elems)

typedef __attribute__((ext_vector_type(8))) unsigned short ushort8;
typedef __bf16 bf16x8 __attribute__((ext_vector_type(8)));
typedef float float4v __attribute__((ext_vector_type(4)));

__device__ __forceinline__ float bf2f(unsigned short u) {
    union { unsigned int i; float f; } x; x.i = ((unsigned int)u) << 16; return x.f;
}
__device__ __forceinline__ unsigned short f2bf(float f) {
    union { float f; unsigned int i; } x; x.f = f;
    unsigned int r = x.i + 0x7fffu + ((x.i >> 16) & 1u);  // RNE
    return (unsigned short)(r >> 16);
}
__device__ __forceinline__ unsigned int pk2(float a, float b) {
    return (unsigned int)f2bf(a) | ((unsigned int)f2bf(b) << 16);
}

// blocks 0..127: Wq1 = Wq@W1 (f32); 128..255: Wk1 = Wk@W1 (f32);
// 256..383: W21t[j][k] = (Wp2@W1)[k][j] in bf16; block 384: bvec.
__global__ void prep_kernel(const float* __restrict__ Wq, const float* __restrict__ Wk,
                            const float* __restrict__ Wp2, const float* __restrict__ W1,
                            const float* __restrict__ b1, const float* __restrict__ bp2,
                            float* __restrict__ Wq1, float* __restrict__ Wk1,
                            unsigned short* __restrict__ W21t, float* __restrict__ bvec) {
    int bx = blockIdx.x, j = threadIdx.x;
    __shared__ float xr[CC];
    if (bx < 384) {
        int r = bx & 127;
        const float* X = (bx < 128) ? Wq : (bx < 256) ? Wk : Wp2;
        xr[j] = X[r * CC + j];
        __syncthreads();
        float s = 0.f;
#pragma unroll 4
        for (int t = 0; t < CC; ++t) s = fmaf(xr[t], W1[t * CC + j], s);
        if (bx < 128)      Wq1[r * CC + j] = s;
        else if (bx < 256) Wk1[r * CC + j] = s;
        else               W21t[j * CC + r] = f2bf(s);   // transposed
    } else {
        float s = b1[j];
        for (int c = 0; c < CC; ++c) s = fmaf(bp2[c], W1[c * CC + j], s);
        bvec[j] = s;
    }
}

// which==0: qwtb[n][j][b] = bf16( (x@Wq1)[n,b][j] )  (transposed, bf16)
// which==1: kw = x@Wk1 (f32);  which==2: v = x@Wv (f32)
__global__ __launch_bounds__(256) void qkv_kernel(
    const float* __restrict__ x, const float* __restrict__ Wq1,
    const float* __restrict__ Wk1, const float* __restrict__ Wv,
    unsigned short* __restrict__ qwtb, float* __restrict__ kw,
    float* __restrict__ v) {
    __shared__ float Ws[CC * CC];
    __shared__ float xs[32 * CC];
    __shared__ float tq[CC * 32];
    int t = threadIdx.x, which = blockIdx.y;
    const float* W = (which == 0) ? Wq1 : (which == 1) ? Wk1 : Wv;
    int row0 = blockIdx.x * 32;
#pragma unroll 8
    for (int i = 0; i < 64; ++i) Ws[i * 256 + t] = W[i * 256 + t];
#pragma unroll 8
    for (int i = 0; i < 16; ++i) xs[i * 256 + t] = x[row0 * CC + i * 256 + t];
    __syncthreads();
    int j = t & 127, rh = t >> 7;
    if (which == 0) {
        for (int r = rh; r < 32; r += 2) {
            float s = 0.f;
#pragma unroll 4
            for (int c = 0; c < CC; ++c) s = fmaf(xs[r * CC + c], Ws[c * CC + j], s);
            tq[j * 32 + r] = s;
        }
        __syncthreads();
        int n = row0 >> 8, b0 = row0 & 255;
#pragma unroll
        for (int it = 0; it < 16; ++it) {
            int idx = it * 256 + t;
            int jj = idx >> 5, bl = idx & 31;
            qwtb[(n * CC + jj) * PP + b0 + bl] = f2bf(tq[jj * 32 + bl]);
        }
    } else {
        float* o = (which == 1) ? kw : v;
        for (int r = rh; r < 32; r += 2) {
            float s = 0.f;
#pragma unroll 4
            for (int c = 0; c < CC; ++c) s = fmaf(xs[r * CC + c], Ws[c * CC + j], s);
            o[(row0 + r) * CC + j] = s;
        }
    }
}

// One block per (n,a). A-operand built in registers (no As LDS, no staging barriers).
__global__ __launch_bounds__(256, 3) void attn_kernel(
    const float* __restrict__ x, const float* __restrict__ pos,
    const float* __restrict__ Wp1, const float* __restrict__ bp1,
    const float* __restrict__ W2, const float* __restrict__ b2,
    const unsigned short* __restrict__ W21t, const float* __restrict__ bvec,
    const unsigned short* __restrict__ qwtb, const float* __restrict__ kw,
    const float* __restrict__ v, float* __restrict__ out)
{
    __shared__ __attribute__((aligned(16))) unsigned short Bs[128 * APAD]; // [j][k]
    __shared__ float p0s[PP], p1s[PP];
    __shared__ float wa[CC], wb[CC], bpv[CC];
    __shared__ float logits[PP];
    __shared__ float red[8];
    __shared__ float avred[CC];

    const int t = threadIdx.x;
    const int n = blockIdx.x >> 8, a = blockIdx.x & 255;
    const int lane = t & 63, wv = t >> 6;
    const int ln = lane & 15, quad = lane >> 4;

    if (t < CC) {
        wa[t]  = Wp1[t];
        wb[t]  = Wp1[CC + t];
        bpv[t] = bp1[t];
    }
    {
        const float2* pr = (const float2*)(pos + (size_t)(n * PP + a) * PP * 2);
        float2 pp = pr[t];
        p0s[t] = pp.x;
        p1s[t] = pp.y;
    }
    {   // stage Bs (W21 transposed, bf16): 2 threads per row
        int j = t >> 1, p = t & 1;
        const ushort8* src = (const ushort8*)(W21t + j * CC + p * 64);
        ushort8* dst = (ushort8*)(Bs + j * APAD + p * 64);
#pragma unroll
        for (int i = 0; i < 8; ++i) dst[i] = src[i];
    }
    const float b2f = b2[0];

    // per-lane epilogue constants (col j = nt*16 + ln)
    float w2v[8], kbv[8];
    {
        const float* kwrow = kw + (size_t)(n * PP + a) * CC;
#pragma unroll
        for (int nt = 0; nt < 8; ++nt) {
            int j = nt * 16 + ln;
            w2v[nt] = W2[j];
            kbv[nt] = bvec[j] - kwrow[j];
        }
    }
    __syncthreads();

    for (int chunk = 0; chunk < 2; ++chunk) {
        float P0[2], P1[2];
#pragma unroll
        for (int i = 0; i < 2; ++i) {
            int bl = chunk * 128 + wv * 32 + i * 16 + ln;
            P0[i] = p0s[bl];
            P1[i] = p1s[bl];
        }

        float4v acc[2][8];
#pragma unroll
        for (int i = 0; i < 2; ++i)
#pragma unroll
            for (int j = 0; j < 8; ++j) acc[i][j] = (float4v)0.f;

#pragma unroll
        for (int kk = 0; kk < 128; kk += 32) {
            const int ko = kk + quad * 8;
            // A-fragments in registers: A[m=ln][k=ko+e], row = wv*32+i*16+ln
            float4 a0 = *(const float4*)&wa[ko],  a1 = *(const float4*)&wa[ko + 4];
            float4 c0 = *(const float4*)&wb[ko],  c1 = *(const float4*)&wb[ko + 4];
            float4 d0 = *(const float4*)&bpv[ko], d1 = *(const float4*)&bpv[ko + 4];
            bf16x8 af[2];
#pragma unroll
            for (int i = 0; i < 2; ++i) {
                float h0 = fmaxf(fmaf(P0[i], a0.x, fmaf(P1[i], c0.x, d0.x)), 0.f);
                float h1 = fmaxf(fmaf(P0[i], a0.y, fmaf(P1[i], c0.y, d0.y)), 0.f);
                float h2 = fmaxf(fmaf(P0[i], a0.z, fmaf(P1[i], c0.z, d0.z)), 0.f);
                float h3 = fmaxf(fmaf(P0[i], a0.w, fmaf(P1[i], c0.w, d0.w)), 0.f);
                float h4 = fmaxf(fmaf(P0[i], a1.x, fmaf(P1[i], c1.x, d1.x)), 0.f);
                float h5 = fmaxf(fmaf(P0[i], a1.y, fmaf(P1[i], c1.y, d1.y)), 0.f);
                float h6 = fmaxf(fmaf(P0[i], a1.z, fmaf(P1[i], c1.z, d1.z)), 0.f);
                float h7 = fmaxf(fmaf(P0[i], a1.w, fmaf(P1[i], c1.w, d1.w)), 0.f);
                union { bf16x8 v8; unsigned int u[4]; } cv;
                cv.u[0] = pk2(h0, h1); cv.u[1] = pk2(h2, h3);
                cv.u[2] = pk2(h4, h5); cv.u[3] = pk2(h6, h7);
                af[i] = cv.v8;
            }
#pragma unroll
            for (int j = 0; j < 8; ++j) {
                bf16x8 bfr = *(const bf16x8*)(Bs + (j * 16 + ln) * APAD + ko);
                acc[0][j] = __builtin_amdgcn_mfma_f32_16x16x32_bf16(af[0], bfr, acc[0][j], 0, 0, 0);
                acc[1][j] = __builtin_amdgcn_mfma_f32_16x16x32_bf16(af[1], bfr, acc[1][j], 0, 0, 0);
            }
        }

        // load qw values for epilogue (bf16, transposed layout: [n][j][b])
        ushort4 qv4[2][8];
#pragma unroll
        for (int i = 0; i < 2; ++i)
#pragma unroll
            for (int nt = 0; nt < 8; ++nt)
                qv4[i][nt] = *(const ushort4*)(qwtb
                    + (size_t)(n * CC + nt * 16 + ln) * PP
                    + chunk * 128 + wv * 32 + i * 16 + quad * 4);

        // epilogue: D row = quad*4 + r, col = nt*16 + ln
#pragma unroll
        for (int i = 0; i < 2; ++i) {
            float s0 = 0.f, s1 = 0.f, s2 = 0.f, s3 = 0.f;
#pragma unroll
            for (int nt = 0; nt < 8; ++nt) {
                float kb = kbv[nt], w2 = w2v[nt];
                s0 = fmaf(fmaxf(acc[i][nt][0] + bf2f(qv4[i][nt].x) + kb, 0.f), w2, s0);
                s1 = fmaf(fmaxf(acc[i][nt][1] + bf2f(qv4[i][nt].y) + kb, 0.f), w2, s1);
                s2 = fmaf(fmaxf(acc[i][nt][2] + bf2f(qv4[i][nt].z) + kb, 0.f), w2, s2);
                s3 = fmaf(fmaxf(acc[i][nt][3] + bf2f(qv4[i][nt].w) + kb, 0.f), w2, s3);
            }
            float sr[4] = {s0, s1, s2, s3};
#pragma unroll
            for (int r = 0; r < 4; ++r) {
                float s = sr[r];
                s += __shfl_xor(s, 1);
                s += __shfl_xor(s, 2);
                s += __shfl_xor(s, 4);
                s += __shfl_xor(s, 8);
                if (ln == 0) logits[chunk * 128 + wv * 32 + i * 16 + quad * 4 + r] = s + b2f;
            }
        }
    }
    __syncthreads();   // logits ready

    // ---- softmax over 256 logits: wave shfl reductions ----
    float lv = logits[t];
    float wm = lv;
#pragma unroll
    for (int d = 1; d < 64; d <<= 1) wm = fmaxf(wm, __shfl_xor(wm, d));
    if (lane == 0) red[wv] = wm;
    __syncthreads();
    float m = fmaxf(fmaxf(red[0], red[1]), fmaxf(red[2], red[3]));
    float e = __expf(lv - m);
    float es = e;
#pragma unroll
    for (int d = 1; d < 64; d <<= 1) es += __shfl_xor(es, d);
    if (lane == 0) red[4 + wv] = es;
    __syncthreads();
    float denom = red[4] + red[5] + red[6] + red[7];
    logits[t] = e / denom;
    __syncthreads();

    // ---- out[n,a,c] = x[n,a,c] + sum_b att[b] * v[n,b,c] ----
    int c = t & 127, h2 = t >> 7;
    const float* vp = v + (size_t)(n * PP + h2 * 128) * CC + c;
    float acc0 = 0.f;
#pragma unroll 8
    for (int b = 0; b < 128; ++b)
        acc0 = fmaf(logits[h2 * 128 + b], vp[(size_t)b * CC], acc0);
    if (h2 == 1) avred[c] = acc0;
    __syncthreads();
    if (h2 == 0) {
        int oidx = (n * PP + a) * CC + c;
        out[oidx] = x[oidx] + acc0 + avred[c];
    }
}

extern "C" void kernel_launch(void* const* d_in, const int* in_sizes, int n_in,
                              void* d_out, int out_size, void* d_ws, size_t ws_size,
                              hipStream_t stream) {
    const float* x   = (const float*)d_in[0];
    const float* pos = (const float*)d_in[1];
    const float* Wq  = (const float*)d_in[2];
    const float* Wk  = (const float*)d_in[3];
    const float* Wv  = (const float*)d_in[4];
    const float* W1  = (const float*)d_in[5];
    const float* b1  = (const float*)d_in[6];
    const float* W2  = (const float*)d_in[7];
    const float* b2  = (const float*)d_in[8];
    const float* Wp1 = (const float*)d_in[9];
    const float* bp1 = (const float*)d_in[10];
    const float* Wp2 = (const float*)d_in[11];
    const float* bp2 = (const float*)d_in[12];
    float* out = (float*)d_out;

    float* ws   = (float*)d_ws;
    float* Wq1  = ws;                  // 16384 f32
    float* Wk1  = Wq1 + 16384;         // 16384 f32
    float* bvec = Wk1 + 16384;         // 128 f32
    float* kw   = bvec + 128;          // 262144 f32
    float* v    = kw + 262144;         // 262144 f32
    unsigned short* qwtb = (unsigned short*)(v + 262144);  // 262144 bf16
    unsigned short* W21t = qwtb + 262144;                  // 16384 bf16

    prep_kernel<<<385, 128, 0, stream>>>(Wq, Wk, Wp2, W1, b1, bp2, Wq1, Wk1, W21t, bvec);
    qkv_kernel<<<dim3(64, 3), 256, 0, stream>>>(x, Wq1, Wk1, Wv, qwtb, kw, v);
    attn_kernel<<<NB * PP, 256, 0, stream>>>(x, pos, Wp1, bp1, W2, b2,
                                             W21t, bvec, qwtb, kw, v, out);
}

// Round 7
// 158.737 us; speedup vs baseline: 2.8495x; 2.8495x over previous
//
#include <hip/hip_runtime.h>
#include <hip/hip_bf16.h>

#define NB 8
#define PP 256
#define CC 128
#define APAD 136   // padded k-stride for Bs (bf16 elems)
#define XS 132     // padded row stride for qkv x-tile (f32 elems)

typedef __attribute__((ext_vector_type(8))) unsigned short ushort8;
typedef __bf16 bf16x8 __attribute__((ext_vector_type(8)));
typedef float float4v __attribute__((ext_vector_type(4)));

__device__ __forceinline__ float bf2f(unsigned short u) {
    union { unsigned int i; float f; } x; x.i = ((unsigned int)u) << 16; return x.f;
}
__device__ __forceinline__ unsigned short f2bf(float f) {
    union { float f; unsigned int i; } x; x.f = f;
    unsigned int r = x.i + 0x7fffu + ((x.i >> 16) & 1u);  // RNE
    return (unsigned short)(r >> 16);
}
__device__ __forceinline__ unsigned int pk2(float a, float b) {
    return (unsigned int)f2bf(a) | ((unsigned int)f2bf(b) << 16);
}

// blocks 0..127: Wq1 = Wq@W1 (f32); 128..255: Wk1 = Wk@W1 (f32);
// 256..383: W21t[j][k] = (Wp2@W1)[k][j] in bf16; block 384: bvec.
__global__ void prep_kernel(const float* __restrict__ Wq, const float* __restrict__ Wk,
                            const float* __restrict__ Wp2, const float* __restrict__ W1,
                            const float* __restrict__ b1, const float* __restrict__ bp2,
                            float* __restrict__ Wq1, float* __restrict__ Wk1,
                            unsigned short* __restrict__ W21t, float* __restrict__ bvec) {
    int bx = blockIdx.x, j = threadIdx.x;
    __shared__ float xr[CC];
    if (bx < 384) {
        int r = bx & 127;
        const float* X = (bx < 128) ? Wq : (bx < 256) ? Wk : Wp2;
        xr[j] = X[r * CC + j];
        __syncthreads();
        float s = 0.f;
#pragma unroll 4
        for (int t = 0; t < CC; ++t) s = fmaf(xr[t], W1[t * CC + j], s);
        if (bx < 128)      Wq1[r * CC + j] = s;
        else if (bx < 256) Wk1[r * CC + j] = s;
        else               W21t[j * CC + r] = f2bf(s);   // transposed
    } else {
        float s = b1[j];
        for (int c = 0; c < CC; ++c) s = fmaf(bp2[c], W1[c * CC + j], s);
        bvec[j] = s;
    }
}

// which==0: qwtb[n][j][b] = bf16( (x@Wq1)[n,b][j] )  (transposed, bf16)
// which==1: kw = x@Wk1 (f32);  which==2: v = x@Wv (f32)
// 4x4 register tile per thread; xs padded to stride 132 (conflict-free reads).
__global__ __launch_bounds__(256) void qkv_kernel(
    const float* __restrict__ x, const float* __restrict__ Wq1,
    const float* __restrict__ Wk1, const float* __restrict__ Wv,
    unsigned short* __restrict__ qwtb, float* __restrict__ kw,
    float* __restrict__ v) {
    __shared__ float Ws[CC * CC];
    __shared__ float xs[32 * XS];
    int t = threadIdx.x, which = blockIdx.y;
    const float* W = (which == 0) ? Wq1 : (which == 1) ? Wk1 : Wv;
    int row0 = blockIdx.x * 32;
#pragma unroll 8
    for (int i = 0; i < 64; ++i) Ws[i * 256 + t] = W[i * 256 + t];
#pragma unroll 4
    for (int i = 0; i < 16; ++i) {
        int idx = i * 256 + t;
        int r = idx >> 7, c = idx & 127;
        xs[r * XS + c] = x[(size_t)(row0 + r) * CC + c];
    }
    __syncthreads();
    int tc = t & 31, tr = t >> 5;
    int j0 = tc * 4, r0 = tr * 4;
    float acc[4][4];
#pragma unroll
    for (int i = 0; i < 4; ++i)
#pragma unroll
        for (int jj = 0; jj < 4; ++jj) acc[i][jj] = 0.f;
#pragma unroll 2
    for (int c = 0; c < CC; ++c) {
        float4 w4 = *(const float4*)&Ws[c * CC + j0];
        float x0 = xs[(r0 + 0) * XS + c], x1 = xs[(r0 + 1) * XS + c];
        float x2 = xs[(r0 + 2) * XS + c], x3 = xs[(r0 + 3) * XS + c];
        acc[0][0] = fmaf(x0, w4.x, acc[0][0]); acc[0][1] = fmaf(x0, w4.y, acc[0][1]);
        acc[0][2] = fmaf(x0, w4.z, acc[0][2]); acc[0][3] = fmaf(x0, w4.w, acc[0][3]);
        acc[1][0] = fmaf(x1, w4.x, acc[1][0]); acc[1][1] = fmaf(x1, w4.y, acc[1][1]);
        acc[1][2] = fmaf(x1, w4.z, acc[1][2]); acc[1][3] = fmaf(x1, w4.w, acc[1][3]);
        acc[2][0] = fmaf(x2, w4.x, acc[2][0]); acc[2][1] = fmaf(x2, w4.y, acc[2][1]);
        acc[2][2] = fmaf(x2, w4.z, acc[2][2]); acc[2][3] = fmaf(x2, w4.w, acc[2][3]);
        acc[3][0] = fmaf(x3, w4.x, acc[3][0]); acc[3][1] = fmaf(x3, w4.y, acc[3][1]);
        acc[3][2] = fmaf(x3, w4.z, acc[3][2]); acc[3][3] = fmaf(x3, w4.w, acc[3][3]);
    }
    if (which == 0) {
        int n = row0 >> 8, b0 = row0 & 255;
#pragma unroll
        for (int jj = 0; jj < 4; ++jj) {
            ushort4 pk;
            pk.x = f2bf(acc[0][jj]); pk.y = f2bf(acc[1][jj]);
            pk.z = f2bf(acc[2][jj]); pk.w = f2bf(acc[3][jj]);
            *(ushort4*)(qwtb + (size_t)(n * CC + j0 + jj) * PP + b0 + r0) = pk;
        }
    } else {
        float* o = (which == 1) ? kw : v;
#pragma unroll
        for (int i = 0; i < 4; ++i)
            *(float4*)&o[(size_t)(row0 + r0 + i) * CC + j0] =
                make_float4(acc[i][0], acc[i][1], acc[i][2], acc[i][3]);
    }
}

// One block per (n,a). A-operand built in registers; 4 chunks x 64 rows;
// one 16-row m-tile per wave per chunk (acc[8] = 32 VGPRs, no spill at waves=3).
__global__ __launch_bounds__(256, 3) void attn_kernel(
    const float* __restrict__ x, const float* __restrict__ pos,
    const float* __restrict__ Wp1, const float* __restrict__ bp1,
    const float* __restrict__ W2, const float* __restrict__ b2,
    const unsigned short* __restrict__ W21t, const float* __restrict__ bvec,
    const unsigned short* __restrict__ qwtb, const float* __restrict__ kw,
    const float* __restrict__ v, float* __restrict__ out)
{
    __shared__ __attribute__((aligned(16))) unsigned short Bs[128 * APAD]; // [j][k]
    __shared__ float p0s[PP], p1s[PP];
    __shared__ float wa[CC], wb[CC], bpv[CC];
    __shared__ float logits[PP];
    __shared__ float red[8];
    __shared__ float avred[CC];

    const int t = threadIdx.x;
    const int n = blockIdx.x >> 8, a = blockIdx.x & 255;
    const int lane = t & 63, wv = t >> 6;
    const int ln = lane & 15, quad = lane >> 4;

    if (t < CC) {
        wa[t]  = Wp1[t];
        wb[t]  = Wp1[CC + t];
        bpv[t] = bp1[t];
    }
    {
        const float2* pr = (const float2*)(pos + (size_t)(n * PP + a) * PP * 2);
        float2 pp = pr[t];
        p0s[t] = pp.x;
        p1s[t] = pp.y;
    }
    {   // stage Bs (W21 transposed, bf16): 2 threads per row
        int j = t >> 1, p = t & 1;
        const ushort8* src = (const ushort8*)(W21t + j * CC + p * 64);
        ushort8* dst = (ushort8*)(Bs + j * APAD + p * 64);
#pragma unroll
        for (int i = 0; i < 8; ++i) dst[i] = src[i];
    }
    const float b2f = b2[0];

    // per-lane epilogue constants (col j = nt*16 + ln)
    float w2v[8], kbv[8];
    {
        const float* kwrow = kw + (size_t)(n * PP + a) * CC;
#pragma unroll
        for (int nt = 0; nt < 8; ++nt) {
            int j = nt * 16 + ln;
            w2v[nt] = W2[j];
            kbv[nt] = bvec[j] - kwrow[j];
        }
    }
    __syncthreads();

#pragma unroll 1
    for (int chunk = 0; chunk < 4; ++chunk) {
        const int rbase = chunk * 64 + wv * 16;
        const float P0 = p0s[rbase + ln];
        const float P1 = p1s[rbase + ln];

        // prefetch qw epilogue values (bf16 transposed [n][j][b]) — drains behind MFMA
        ushort4 qv4[8];
#pragma unroll
        for (int nt = 0; nt < 8; ++nt)
            qv4[nt] = *(const ushort4*)(qwtb + (size_t)(n * CC + nt * 16 + ln) * PP
                                        + rbase + quad * 4);

        float4v acc[8];
#pragma unroll
        for (int j = 0; j < 8; ++j) acc[j] = (float4v)0.f;

#pragma unroll 1
        for (int kk = 0; kk < 128; kk += 32) {
            const int ko = kk + quad * 8;
            // A-fragment in registers: A[m=ln][k=ko+e]
            float4 a0 = *(const float4*)&wa[ko],  a1 = *(const float4*)&wa[ko + 4];
            float4 c0 = *(const float4*)&wb[ko],  c1 = *(const float4*)&wb[ko + 4];
            float4 d0 = *(const float4*)&bpv[ko], d1 = *(const float4*)&bpv[ko + 4];
            float h0 = fmaxf(fmaf(P0, a0.x, fmaf(P1, c0.x, d0.x)), 0.f);
            float h1 = fmaxf(fmaf(P0, a0.y, fmaf(P1, c0.y, d0.y)), 0.f);
            float h2 = fmaxf(fmaf(P0, a0.z, fmaf(P1, c0.z, d0.z)), 0.f);
            float h3 = fmaxf(fmaf(P0, a0.w, fmaf(P1, c0.w, d0.w)), 0.f);
            float h4 = fmaxf(fmaf(P0, a1.x, fmaf(P1, c1.x, d1.x)), 0.f);
            float h5 = fmaxf(fmaf(P0, a1.y, fmaf(P1, c1.y, d1.y)), 0.f);
            float h6 = fmaxf(fmaf(P0, a1.z, fmaf(P1, c1.z, d1.z)), 0.f);
            float h7 = fmaxf(fmaf(P0, a1.w, fmaf(P1, c1.w, d1.w)), 0.f);
            union { bf16x8 v8; unsigned int u[4]; } cv;
            cv.u[0] = pk2(h0, h1); cv.u[1] = pk2(h2, h3);
            cv.u[2] = pk2(h4, h5); cv.u[3] = pk2(h6, h7);
            bf16x8 af = cv.v8;
#pragma unroll
            for (int j = 0; j < 8; ++j) {
                bf16x8 bfr = *(const bf16x8*)(Bs + (j * 16 + ln) * APAD + ko);
                acc[j] = __builtin_amdgcn_mfma_f32_16x16x32_bf16(af, bfr, acc[j], 0, 0, 0);
            }
        }

        // epilogue: D row = quad*4 + r, col = nt*16 + ln
        float s0 = 0.f, s1 = 0.f, s2 = 0.f, s3 = 0.f;
#pragma unroll
        for (int nt = 0; nt < 8; ++nt) {
            float kb = kbv[nt], w2 = w2v[nt];
            s0 = fmaf(fmaxf(acc[nt][0] + bf2f(qv4[nt].x) + kb, 0.f), w2, s0);
            s1 = fmaf(fmaxf(acc[nt][1] + bf2f(qv4[nt].y) + kb, 0.f), w2, s1);
            s2 = fmaf(fmaxf(acc[nt][2] + bf2f(qv4[nt].z) + kb, 0.f), w2, s2);
            s3 = fmaf(fmaxf(acc[nt][3] + bf2f(qv4[nt].w) + kb, 0.f), w2, s3);
        }
        float sr[4] = {s0, s1, s2, s3};
#pragma unroll
        for (int r = 0; r < 4; ++r) {
            float s = sr[r];
            s += __shfl_xor(s, 1);
            s += __shfl_xor(s, 2);
            s += __shfl_xor(s, 4);
            s += __shfl_xor(s, 8);
            if (ln == 0) logits[rbase + quad * 4 + r] = s + b2f;
        }
    }
    __syncthreads();   // logits ready

    // ---- softmax over 256 logits: wave shfl reductions ----
    float lv = logits[t];
    float wm = lv;
#pragma unroll
    for (int d = 1; d < 64; d <<= 1) wm = fmaxf(wm, __shfl_xor(wm, d));
    if (lane == 0) red[wv] = wm;
    __syncthreads();
    float m = fmaxf(fmaxf(red[0], red[1]), fmaxf(red[2], red[3]));
    float e = __expf(lv - m);
    float es = e;
#pragma unroll
    for (int d = 1; d < 64; d <<= 1) es += __shfl_xor(es, d);
    if (lane == 0) red[4 + wv] = es;
    __syncthreads();
    float denom = red[4] + red[5] + red[6] + red[7];
    logits[t] = e / denom;
    __syncthreads();

    // ---- out[n,a,c] = x[n,a,c] + sum_b att[b] * v[n,b,c] ----
    int c = t & 127, h2 = t >> 7;
    const float* vp = v + (size_t)(n * PP + h2 * 128) * CC + c;
    float acc0 = 0.f;
#pragma unroll 8
    for (int b = 0; b < 128; ++b)
        acc0 = fmaf(logits[h2 * 128 + b], vp[(size_t)b * CC], acc0);
    if (h2 == 1) avred[c] = acc0;
    __syncthreads();
    if (h2 == 0) {
        int oidx = (n * PP + a) * CC + c;
        out[oidx] = x[oidx] + acc0 + avred[c];
    }
}

extern "C" void kernel_launch(void* const* d_in, const int* in_sizes, int n_in,
                              void* d_out, int out_size, void* d_ws, size_t ws_size,
                              hipStream_t stream) {
    const float* x   = (const float*)d_in[0];
    const float* pos = (const float*)d_in[1];
    const float* Wq  = (const float*)d_in[2];
    const float* Wk  = (const float*)d_in[3];
    const float* Wv  = (const float*)d_in[4];
    const float* W1  = (const float*)d_in[5];
    const float* b1  = (const float*)d_in[6];
    const float* W2  = (const float*)d_in[7];
    const float* b2  = (const float*)d_in[8];
    const float* Wp1 = (const float*)d_in[9];
    const float* bp1 = (const float*)d_in[10];
    const float* Wp2 = (const float*)d_in[11];
    const float* bp2 = (const float*)d_in[12];
    float* out = (float*)d_out;

    float* ws   = (float*)d_ws;
    float* Wq1  = ws;                  // 16384 f32
    float* Wk1  = Wq1 + 16384;         // 16384 f32
    float* bvec = Wk1 + 16384;         // 128 f32
    float* kw   = bvec + 128;          // 262144 f32
    float* v    = kw + 262144;         // 262144 f32
    unsigned short* qwtb = (unsigned short*)(v + 262144);  // 262144 bf16
    unsigned short* W21t = qwtb + 262144;                  // 16384 bf16

    prep_kernel<<<385, 128, 0, stream>>>(Wq, Wk, Wp2, W1, b1, bp2, Wq1, Wk1, W21t, bvec);
    qkv_kernel<<<dim3(64, 3), 256, 0, stream>>>(x, Wq1, Wk1, Wv, qwtb, kw, v);
    attn_kernel<<<NB * PP, 256, 0, stream>>>(x, pos, Wp1, bp1, W2, b2,
                                             W21t, bvec, qwtb, kw, v, out);
}